// Round 8
// baseline (145.057 us; speedup 1.0000x reference)
//
#include <hip/hip_runtime.h>
#include <hip/hip_bf16.h>

// LightGCNConv: out[dst] = sum_e w[e] * x[src_e], N=100000, d=64, E=1250000.
//
// R1: 80M fp32 device atomics -> 275us kernel (atomics bypass cache; WRITE=320MB).
// R2: exact CSR; fill 8x write amp 90us + gather 88us -> 295 total.
// R3: per-bucket LDS-accumulate gather, 1563 blocks -> 471us. REVERTED.
// R4: L2-resident CSR build + reg-accumulate gather -> 200 total.
// R5: bf16 x + fixed-cap buckets -> 158.7. Harness poison/restore of 256MiB
//     d_ws + inputs = ~65us fixed overhead inside dur_us (top-5 = fillBuffer).
// R6: cast+bin fusion, 4-node/wave gather -> 158.4 (neutral).
// R7: sort+gather fused per bucket (sorted payload LDS-resident, no global
//     round-trip) -> 135.6. Controllable pipeline ~70us vs ~21us traffic floor
//     => issue/latency-bound.
// R8: (a) gather 8 nodes/wave: 8 lanes x uint4(16B) per row -> half the VMEM
//         issues/edge; (b) LDS bitonic degree-sort of the 128 bucket nodes so
//         co-wave octants have matched trip counts (Poisson max-of-8 waste
//         ~55% -> ~5%), single pass; (c) castbin int4/float4 edge loads.
//     Fallback chain: A -> B (R4 exact, proven) -> C (R1).

#define N_NODES   100000
#define N_FEAT    64

// ---------------- Path A ----------------
#define A_BSH     7
#define A_NPB     (1 << A_BSH)                       // 128 nodes/bucket
#define A_KB      ((N_NODES + A_NPB - 1) >> A_BSH)   // 782 buckets
#define A_CAP     2048                               // slots/bucket (mean 1598)
#define A_FCHUNK  4096                               // edges per bin block
#define A_OVCAP   65536
#define NBIN      ((1250000 + A_FCHUNK - 1) / A_FCHUNK)   // 306 (E known)
#define NCAST     391   // 391*1024*4 float4 = 1.6016M >= 1.6M

// fused: blocks [0,NBIN) bin edges; blocks [NBIN,NBIN+NCAST) cast x->bf16
__global__ __launch_bounds__(1024) void k_castbin(
    const float* __restrict__ x, ushort* __restrict__ xb,
    const int* __restrict__ ei, const float* __restrict__ w,
    int* __restrict__ bcur, int2* __restrict__ stg,
    int* __restrict__ ovf, int* __restrict__ ovcnt, int E) {
    int t = threadIdx.x;
    if (blockIdx.x >= NBIN) {
        // ---- cast role ----
        int cb = blockIdx.x - NBIN;
        #pragma unroll
        for (int k = 0; k < 4; ++k) {
            int i4 = cb * 4096 + k * 1024 + t;           // float4 index
            if (i4 < N_NODES * N_FEAT / 4) {
                float4 v = ((const float4*)x)[i4];
                uint4 u = *(uint4*)&v;
                ushort4 r;
                r.x = (ushort)((u.x + 0x7FFFu + ((u.x >> 16) & 1)) >> 16);
                r.y = (ushort)((u.y + 0x7FFFu + ((u.y >> 16) & 1)) >> 16);
                r.z = (ushort)((u.z + 0x7FFFu + ((u.z >> 16) & 1)) >> 16);
                r.w = (ushort)((u.w + 0x7FFFu + ((u.w >> 16) & 1)) >> 16);
                ((ushort4*)xb)[i4] = r;
            }
        }
        return;
    }
    // ---- bin role: one int4/float4 load per array per thread ----
    __shared__ int h[A_KB];
    for (int b = t; b < A_KB; b += 1024) h[b] = 0;
    __syncthreads();
    int e0 = blockIdx.x * A_FCHUNK;
    int ebase = e0 + t * 4;
    int4 d4; int4 s4; float4 w4;
    if (ebase + 3 < E) {
        d4 = ((const int4*)(ei + E))[(e0 >> 2) + t];
        s4 = ((const int4*)ei)[(e0 >> 2) + t];
        w4 = ((const float4*)w)[(e0 >> 2) + t];
    } else {
        int* dp = (int*)&d4; int* sp = (int*)&s4; float* wp = (float*)&w4;
        #pragma unroll
        for (int c = 0; c < 4; ++c) {
            int e = ebase + c;
            dp[c] = (e < E) ? ei[E + e] : -1;
            sp[c] = (e < E) ? ei[e] : 0;
            wp[c] = (e < E) ? w[e] : 0.f;
        }
    }
    const int* dp = (const int*)&d4;
    const int* sp = (const int*)&s4;
    const float* wp = (const float*)&w4;
    #pragma unroll
    for (int c = 0; c < 4; ++c)
        if (dp[c] >= 0) atomicAdd(&h[dp[c] >> A_BSH], 1);
    __syncthreads();
    for (int b = t; b < A_KB; b += 1024) {
        int c = h[b];
        h[b] = c ? atomicAdd(&bcur[b], c) : 0;   // bucket-local base
    }
    __syncthreads();
    #pragma unroll
    for (int c = 0; c < 4; ++c) {
        if (dp[c] >= 0) {
            int b = dp[c] >> A_BSH;
            int loc = atomicAdd(&h[b], 1);       // LDS int atomic
            if (loc < A_CAP) {
                stg[b * A_CAP + loc] =
                    make_int2(sp[c] | ((dp[c] & (A_NPB - 1)) << 17),
                              __float_as_int(wp[c]));
            } else {
                int oi = atomicAdd(ovcnt, 1);
                if (oi < A_OVCAP) ovf[oi] = ebase + c;
            }
        }
    }
}

// fused per-bucket counting sort (LDS-resident) + degree-matched octant gather
__global__ __launch_bounds__(1024) void k_sortgather(
    const ushort* __restrict__ xb, const int* __restrict__ bcur,
    const int2* __restrict__ stg, float* __restrict__ out) {
    __shared__ int2 buf[A_CAP];      // 16 KB raw payload
    __shared__ int2 srt[A_CAP];      // 16 KB sorted payload
    __shared__ int  hist[A_NPB];     // per-node counts
    __shared__ int  start[A_NPB];    // per-node exclusive offsets
    __shared__ int  cur[A_NPB];      // scan temp / place cursor
    __shared__ int  order[A_NPB];    // packed (deg<<7)|id, sorted desc
    int b = blockIdx.x, t = threadIdx.x;
    int cnt = bcur[b];
    if (cnt > A_CAP) cnt = A_CAP;
    int base = b * A_CAP;

    if (t < A_NPB) hist[t] = 0;
    __syncthreads();
    for (int i = t; i < cnt; i += 1024) {
        int2 p = stg[base + i];
        buf[i] = p;
        atomicAdd(&hist[(p.x >> 17) & (A_NPB - 1)], 1);
    }
    __syncthreads();
    // Hillis-Steele inclusive scan of 128 counts (threads 0..127)
    if (t < A_NPB) cur[t] = hist[t];
    __syncthreads();
    for (int off = 1; off < A_NPB; off <<= 1) {
        int v = (t < A_NPB && t >= off) ? cur[t - off] : 0;
        __syncthreads();
        if (t < A_NPB && t >= off) cur[t] += v;
        __syncthreads();
    }
    if (t < A_NPB) start[t] = (t == 0) ? 0 : cur[t - 1];
    __syncthreads();
    if (t < A_NPB) {
        cur[t] = start[t];
        order[t] = (hist[t] << A_BSH) | t;    // deg<=2048 -> fits
    }
    __syncthreads();
    // place into sorted LDS buffer
    for (int i = t; i < cnt; i += 1024) {
        int2 p = buf[i];
        int pos = atomicAdd(&cur[(p.x >> 17) & (A_NPB - 1)], 1);
        srt[pos] = p;
    }
    // bitonic sort order[] descending by degree (threads 0..127)
    for (int k = 2; k <= A_NPB; k <<= 1) {
        for (int j = k >> 1; j > 0; j >>= 1) {
            if (t < A_NPB) {
                int ixj = t ^ j;
                if (ixj > t) {
                    int a = order[t], c = order[ixj];
                    bool up = ((t & k) == 0);
                    if (up ? (a < c) : (a > c)) { order[t] = c; order[ixj] = a; }
                }
            }
            __syncthreads();
        }
    }
    __syncthreads();

    // gather: 16 waves x 8 octants = 128 slots, degree-matched within wave
    int wid  = t >> 6;                 // 0..15
    int lane = t & 63;
    int s    = wid * 8 + (lane >> 3);  // slot 0..127 (sorted rank)
    int l    = lane & 7;               // uint4 column (8 x 16B = 128B row)
    int ord  = order[s];
    int n    = ord & (A_NPB - 1);
    int deg  = ord >> A_BSH;
    int node = (b << A_BSH) + n;
    int j = start[n], end = start[n] + deg;
    const uint4* xb4 = (const uint4*)xb;
    float acc0[8], acc1[8];
    #pragma unroll
    for (int i = 0; i < 8; ++i) { acc0[i] = 0.f; acc1[i] = 0.f; }
    for (; j + 1 < end; j += 2) {
        int2 p0 = srt[j];
        int2 p1 = srt[j + 1];
        uint4 u0 = xb4[(size_t)(p0.x & 0x1FFFF) * 8 + l];
        uint4 u1 = xb4[(size_t)(p1.x & 0x1FFFF) * 8 + l];
        float w0 = __int_as_float(p0.y), w1 = __int_as_float(p1.y);
        acc0[0] += w0 * __uint_as_float(u0.x << 16);
        acc0[1] += w0 * __uint_as_float(u0.x & 0xFFFF0000u);
        acc0[2] += w0 * __uint_as_float(u0.y << 16);
        acc0[3] += w0 * __uint_as_float(u0.y & 0xFFFF0000u);
        acc0[4] += w0 * __uint_as_float(u0.z << 16);
        acc0[5] += w0 * __uint_as_float(u0.z & 0xFFFF0000u);
        acc0[6] += w0 * __uint_as_float(u0.w << 16);
        acc0[7] += w0 * __uint_as_float(u0.w & 0xFFFF0000u);
        acc1[0] += w1 * __uint_as_float(u1.x << 16);
        acc1[1] += w1 * __uint_as_float(u1.x & 0xFFFF0000u);
        acc1[2] += w1 * __uint_as_float(u1.y << 16);
        acc1[3] += w1 * __uint_as_float(u1.y & 0xFFFF0000u);
        acc1[4] += w1 * __uint_as_float(u1.z << 16);
        acc1[5] += w1 * __uint_as_float(u1.z & 0xFFFF0000u);
        acc1[6] += w1 * __uint_as_float(u1.w << 16);
        acc1[7] += w1 * __uint_as_float(u1.w & 0xFFFF0000u);
    }
    if (j < end) {
        int2 p = srt[j];
        uint4 u = xb4[(size_t)(p.x & 0x1FFFF) * 8 + l];
        float wv = __int_as_float(p.y);
        acc0[0] += wv * __uint_as_float(u.x << 16);
        acc0[1] += wv * __uint_as_float(u.x & 0xFFFF0000u);
        acc0[2] += wv * __uint_as_float(u.y << 16);
        acc0[3] += wv * __uint_as_float(u.y & 0xFFFF0000u);
        acc0[4] += wv * __uint_as_float(u.z << 16);
        acc0[5] += wv * __uint_as_float(u.z & 0xFFFF0000u);
        acc0[6] += wv * __uint_as_float(u.w << 16);
        acc0[7] += wv * __uint_as_float(u.w & 0xFFFF0000u);
    }
    if (node < N_NODES) {
        float4 r0, r1;
        r0.x = acc0[0] + acc1[0]; r0.y = acc0[1] + acc1[1];
        r0.z = acc0[2] + acc1[2]; r0.w = acc0[3] + acc1[3];
        r1.x = acc0[4] + acc1[4]; r1.y = acc0[5] + acc1[5];
        r1.z = acc0[6] + acc1[6]; r1.w = acc0[7] + acc1[7];
        ((float4*)out)[(size_t)node * 16 + l * 2]     = r0;
        ((float4*)out)[(size_t)node * 16 + l * 2 + 1] = r1;
    }
}

// overflow fix-up (normally 0 entries): exact fp32 atomic adds
__global__ __launch_bounds__(256) void k_ovf(
    const float* __restrict__ x, const int* __restrict__ ei,
    const float* __restrict__ w, const int* __restrict__ ovf,
    const int* __restrict__ ovcnt, float* __restrict__ out, int E) {
    int n = *ovcnt;
    if (n > A_OVCAP) n = A_OVCAP;
    int wid  = blockIdx.x * 4 + (threadIdx.x >> 6);
    int lane = threadIdx.x & 63;
    for (int i = wid; i < n; i += gridDim.x * 4) {
        int e = ovf[i];
        float v = w[e] * x[(size_t)ei[e] * N_FEAT + lane];
        atomicAdd(&out[(size_t)ei[E + e] * N_FEAT + lane], v);
    }
}

// ---------------- Path B (R4 exact pipeline, proven 200us) ----------------
#define BSH       8
#define NPB       (1 << BSH)
#define KB        ((N_NODES + NPB - 1) >> BSH)     // 391
#define FCHUNK    8192
#define SORT_CAP  4096

__global__ __launch_bounds__(256) void k_chist(
    const int* __restrict__ ei, int* __restrict__ bcur, int E) {
    __shared__ int h[KB];
    int t = threadIdx.x;
    for (int b = t; b < KB; b += 256) h[b] = 0;
    __syncthreads();
    int e0 = blockIdx.x * FCHUNK;
    #pragma unroll
    for (int k = 0; k < FCHUNK / 256; ++k) {
        int e = e0 + k * 256 + t;
        if (e < E) atomicAdd(&h[ei[E + e] >> BSH], 1);
    }
    __syncthreads();
    for (int b = t; b < KB; b += 256) if (h[b]) atomicAdd(&bcur[b], h[b]);
}

__global__ __launch_bounds__(256) void k_cscan(
    int* __restrict__ bcur, int* __restrict__ boffs) {
    __shared__ int sdata[256];
    int t = threadIdx.x;
    int i0 = 2 * t, i1 = 2 * t + 1;
    int v0 = (i0 < KB) ? bcur[i0] : 0;
    int v1 = (i1 < KB) ? bcur[i1] : 0;
    sdata[t] = v0 + v1; __syncthreads();
    for (int off = 1; off < 256; off <<= 1) {
        int v = (t >= off) ? sdata[t - off] : 0;
        __syncthreads();
        if (t >= off) sdata[t] += v;
        __syncthreads();
    }
    int run = (t == 0) ? 0 : sdata[t - 1];
    if (i0 < KB) { boffs[i0] = run; bcur[i0] = run; }
    run += v0;
    if (i1 < KB) { boffs[i1] = run; bcur[i1] = run; }
    if (t == 255) boffs[KB] = sdata[255];
}

__global__ __launch_bounds__(256) void k_cbin(
    const int* __restrict__ ei, const float* __restrict__ w,
    int* __restrict__ bcur, int2* __restrict__ stg, int E) {
    __shared__ int h[KB];
    int t = threadIdx.x;
    for (int b = t; b < KB; b += 256) h[b] = 0;
    __syncthreads();
    int e0 = blockIdx.x * FCHUNK;
    #pragma unroll
    for (int k = 0; k < FCHUNK / 256; ++k) {
        int e = e0 + k * 256 + t;
        if (e < E) atomicAdd(&h[ei[E + e] >> BSH], 1);
    }
    __syncthreads();
    for (int b = t; b < KB; b += 256) {
        int c = h[b];
        h[b] = c ? atomicAdd(&bcur[b], c) : 0;
    }
    __syncthreads();
    #pragma unroll
    for (int k = 0; k < FCHUNK / 256; ++k) {
        int e = e0 + k * 256 + t;
        if (e < E) {
            int dst = ei[E + e];
            int slot = atomicAdd(&h[dst >> BSH], 1);
            stg[slot] = make_int2(ei[e] | ((dst & (NPB - 1)) << 17),
                                  __float_as_int(w[e]));
        }
    }
}

__global__ __launch_bounds__(256) void k_csort(
    int2* __restrict__ stg, const int* __restrict__ boffs,
    int* __restrict__ offs) {
    __shared__ int2 buf[SORT_CAP];
    __shared__ int  hist[NPB];
    __shared__ int  cur[NPB];
    __shared__ int  sdata[256];
    int b = blockIdx.x, t = threadIdx.x;
    int bg = boffs[b], end = boffs[b + 1], cnt = end - bg;
    for (int n = t; n < NPB; n += 256) hist[n] = 0;
    __syncthreads();
    int nlds = cnt < SORT_CAP ? cnt : SORT_CAP;
    for (int i = t; i < nlds; i += 256) {
        int2 p = stg[bg + i];
        buf[i] = p;
        atomicAdd(&hist[(p.x >> 17) & (NPB - 1)], 1);
    }
    int2 r0{0,0}, r1{0,0}; int nr = 0;
    {
        int i0 = nlds + t, i1 = nlds + 256 + t;
        if (i0 < cnt) { r0 = stg[bg + i0]; atomicAdd(&hist[(r0.x >> 17) & (NPB - 1)], 1); nr = 1; }
        if (i1 < cnt) { r1 = stg[bg + i1]; atomicAdd(&hist[(r1.x >> 17) & (NPB - 1)], 1); nr = 2; }
    }
    __syncthreads();
    int c = hist[t];
    sdata[t] = c; __syncthreads();
    for (int off = 1; off < 256; off <<= 1) {
        int v = (t >= off) ? sdata[t - off] : 0;
        __syncthreads();
        if (t >= off) sdata[t] += v;
        __syncthreads();
    }
    int excl = (t == 0) ? 0 : sdata[t - 1];
    cur[t] = excl;
    int node = (b << BSH) + t;
    if (node < N_NODES) offs[node] = bg + excl;
    if (b == KB - 1 && t == 255) offs[N_NODES] = end;
    __syncthreads();
    for (int i = t; i < nlds; i += 256) {
        int2 p = buf[i];
        int pos = atomicAdd(&cur[(p.x >> 17) & (NPB - 1)], 1);
        stg[bg + pos] = p;
    }
    if (nr >= 1) { int pos = atomicAdd(&cur[(r0.x >> 17) & (NPB - 1)], 1); stg[bg + pos] = r0; }
    if (nr >= 2) { int pos = atomicAdd(&cur[(r1.x >> 17) & (NPB - 1)], 1); stg[bg + pos] = r1; }
}

__global__ __launch_bounds__(256) void k_gather(
    const float* __restrict__ x, const int* __restrict__ offs,
    const int2* __restrict__ stg, float* __restrict__ out) {
    int node = blockIdx.x * 4 + (threadIdx.x >> 6);
    int lane = threadIdx.x & 63;
    if (node >= N_NODES) return;
    int bg = offs[node], end = offs[node + 1];
    float a0 = 0.f, a1 = 0.f, a2 = 0.f, a3 = 0.f;
    int j = bg;
    for (; j + 3 < end; j += 4) {
        int2 p0 = stg[j];
        int2 p1 = stg[j + 1];
        int2 p2 = stg[j + 2];
        int2 p3 = stg[j + 3];
        a0 += __int_as_float(p0.y) * x[(size_t)(p0.x & 0x1FFFF) * N_FEAT + lane];
        a1 += __int_as_float(p1.y) * x[(size_t)(p1.x & 0x1FFFF) * N_FEAT + lane];
        a2 += __int_as_float(p2.y) * x[(size_t)(p2.x & 0x1FFFF) * N_FEAT + lane];
        a3 += __int_as_float(p3.y) * x[(size_t)(p3.x & 0x1FFFF) * N_FEAT + lane];
    }
    for (; j < end; ++j) {
        int2 p = stg[j];
        a0 += __int_as_float(p.y) * x[(size_t)(p.x & 0x1FFFF) * N_FEAT + lane];
    }
    out[(size_t)node * N_FEAT + lane] = (a0 + a1) + (a2 + a3);
}

// ---------------- Path C (R1 scatter) ----------------
__global__ __launch_bounds__(256) void gnn_scatter_kernel(
    const float* __restrict__ x, const int* __restrict__ ei,
    const float* __restrict__ w, float* __restrict__ out, int E) {
    int e = blockIdx.x * 4 + (threadIdx.x >> 6);
    int lane = threadIdx.x & 63;
    if (e >= E) return;
    float v = w[e] * x[(size_t)ei[e] * N_FEAT + lane];
    atomicAdd(&out[(size_t)ei[E + e] * N_FEAT + lane], v);
}

static inline size_t align16(size_t v) { return (v + 15) & ~(size_t)15; }

extern "C" void kernel_launch(void* const* d_in, const int* in_sizes, int n_in,
                              void* d_out, int out_size, void* d_ws, size_t ws_size,
                              hipStream_t stream) {
    const float* x   = (const float*)d_in[0];
    const int*   ei  = (const int*)d_in[1];
    const float* w   = (const float*)d_in[2];
    float*       out = (float*)d_out;
    const int E = in_sizes[2];
    char* ws = (char*)d_ws;

    // ---- Path A layout ----
    size_t a_xb   = 0;
    size_t a_stg  = align16(a_xb + (size_t)N_NODES * N_FEAT * 2);
    size_t a_bcur = align16(a_stg + (size_t)A_KB * A_CAP * 8);    // KB ints + ovcnt
    size_t a_ovf  = align16(a_bcur + (size_t)(A_KB + 1) * 4);
    size_t need_a = a_ovf + (size_t)A_OVCAP * 4;

    if (ws_size >= need_a && E == 1250000) {
        ushort* xb    = (ushort*)(ws + a_xb);
        int2*   stg   = (int2*)(ws + a_stg);
        int*    bcur  = (int*)(ws + a_bcur);
        int*    ovcnt = bcur + A_KB;
        int*    ovf   = (int*)(ws + a_ovf);

        hipMemsetAsync(bcur, 0, (size_t)(A_KB + 1) * 4, stream);
        k_castbin<<<NBIN + NCAST, 1024, 0, stream>>>(
            x, xb, ei, w, bcur, stg, ovf, ovcnt, E);
        k_sortgather<<<A_KB, 1024, 0, stream>>>(xb, bcur, stg, out);
        k_ovf<<<16, 256, 0, stream>>>(x, ei, w, ovf, ovcnt, out, E);
        return;
    }

    // ---- Path B layout (R4) ----
    size_t b_bcur  = 0;
    size_t b_boffs = align16(b_bcur + (size_t)KB * 4);
    size_t b_offs  = align16(b_boffs + (size_t)(KB + 1) * 4);
    size_t b_stg   = align16(b_offs + (size_t)(N_NODES + 1) * 4);
    size_t need_b  = b_stg + (size_t)E * 8;

    if (ws_size >= need_b) {
        int*  bcur  = (int*)(ws + b_bcur);
        int*  boffs = (int*)(ws + b_boffs);
        int*  offs  = (int*)(ws + b_offs);
        int2* stg   = (int2*)(ws + b_stg);
        const int nblk = (E + FCHUNK - 1) / FCHUNK;
        hipMemsetAsync(bcur, 0, (size_t)KB * 4, stream);
        k_chist<<<nblk, 256, 0, stream>>>(ei, bcur, E);
        k_cscan<<<1, 256, 0, stream>>>(bcur, boffs);
        k_cbin<<<nblk, 256, 0, stream>>>(ei, w, bcur, stg, E);
        k_csort<<<KB, 256, 0, stream>>>(stg, boffs, offs);
        k_gather<<<(N_NODES + 3) / 4, 256, 0, stream>>>(x, offs, stg, out);
        return;
    }

    // ---- Path C ----
    hipMemsetAsync(d_out, 0, (size_t)out_size * sizeof(float), stream);
    gnn_scatter_kernel<<<(E + 3) / 4, 256, 0, stream>>>(x, ei, w, out, E);
}

// Round 9
// 140.668 us; speedup vs baseline: 1.0312x; 1.0312x over previous
//
#include <hip/hip_runtime.h>
#include <hip/hip_bf16.h>

// LightGCNConv: out[dst] = sum_e w[e] * x[src_e], N=100000, d=64, E=1250000.
//
// R1: 80M fp32 device atomics -> 275us kernel (atomics bypass cache; WRITE=320MB).
// R2: exact CSR; fill 8x write amp 90us + gather 88us -> 295 total.
// R3: per-bucket LDS-accumulate gather, 1563 blocks -> 471us. REVERTED.
// R4: L2-resident CSR build + reg-accumulate gather -> 200 total.
// R5: bf16 x + fixed-cap buckets -> 158.7. Harness poison/restore of 256MiB
//     d_ws + inputs = ~65us fixed overhead inside dur_us (top-5 = fillBuffer).
// R6: cast+bin fusion, 4-node/wave gather -> 158.4 (neutral).
// R7: sort+gather fused per bucket (sorted payload LDS-resident) -> 135.6.
// R8: octant gather (8 nodes/wave) + bitonic degree-sort -> 145.1 REGRESSION.
//     Lesson: scattered-gather cost is per distinct segment, not per VMEM
//     instruction; octant added VGPR pressure + 28 barriers for nothing.
// R9: revert to R7 quarter-wave gather; deepen unroll 2->4 (MLP: 4 loads in
//     flight/wave, cf. R4's unroll-4 win) + keep int4 castbin loads only.
//     Fallback chain: A -> B (R4 exact, proven) -> C (R1).

#define N_NODES   100000
#define N_FEAT    64

// ---------------- Path A ----------------
#define A_BSH     7
#define A_NPB     (1 << A_BSH)                       // 128 nodes/bucket
#define A_KB      ((N_NODES + A_NPB - 1) >> A_BSH)   // 782 buckets
#define A_CAP     2048                               // slots/bucket (mean 1598)
#define A_FCHUNK  4096                               // edges per bin block
#define A_OVCAP   65536
#define NBIN      ((1250000 + A_FCHUNK - 1) / A_FCHUNK)   // 306 (E known)
#define NCAST     391   // 391*1024*4 float4 = 1.6016M >= 1.6M

// fused: blocks [0,NBIN) bin edges; blocks [NBIN,NBIN+NCAST) cast x->bf16
__global__ __launch_bounds__(1024) void k_castbin(
    const float* __restrict__ x, ushort* __restrict__ xb,
    const int* __restrict__ ei, const float* __restrict__ w,
    int* __restrict__ bcur, int2* __restrict__ stg,
    int* __restrict__ ovf, int* __restrict__ ovcnt, int E) {
    int t = threadIdx.x;
    if (blockIdx.x >= NBIN) {
        // ---- cast role ----
        int cb = blockIdx.x - NBIN;
        #pragma unroll
        for (int k = 0; k < 4; ++k) {
            int i4 = cb * 4096 + k * 1024 + t;           // float4 index
            if (i4 < N_NODES * N_FEAT / 4) {
                float4 v = ((const float4*)x)[i4];
                uint4 u = *(uint4*)&v;
                ushort4 r;
                r.x = (ushort)((u.x + 0x7FFFu + ((u.x >> 16) & 1)) >> 16);
                r.y = (ushort)((u.y + 0x7FFFu + ((u.y >> 16) & 1)) >> 16);
                r.z = (ushort)((u.z + 0x7FFFu + ((u.z >> 16) & 1)) >> 16);
                r.w = (ushort)((u.w + 0x7FFFu + ((u.w >> 16) & 1)) >> 16);
                ((ushort4*)xb)[i4] = r;
            }
        }
        return;
    }
    // ---- bin role: one int4/float4 load per array per thread ----
    __shared__ int h[A_KB];
    for (int b = t; b < A_KB; b += 1024) h[b] = 0;
    __syncthreads();
    int e0 = blockIdx.x * A_FCHUNK;
    int ebase = e0 + t * 4;
    int4 d4; int4 s4; float4 w4;
    if (ebase + 3 < E) {
        d4 = ((const int4*)(ei + E))[(e0 >> 2) + t];
        s4 = ((const int4*)ei)[(e0 >> 2) + t];
        w4 = ((const float4*)w)[(e0 >> 2) + t];
    } else {
        int* dp = (int*)&d4; int* sp = (int*)&s4; float* wp = (float*)&w4;
        #pragma unroll
        for (int c = 0; c < 4; ++c) {
            int e = ebase + c;
            dp[c] = (e < E) ? ei[E + e] : -1;
            sp[c] = (e < E) ? ei[e] : 0;
            wp[c] = (e < E) ? w[e] : 0.f;
        }
    }
    const int* dp = (const int*)&d4;
    const int* sp = (const int*)&s4;
    const float* wp = (const float*)&w4;
    #pragma unroll
    for (int c = 0; c < 4; ++c)
        if (dp[c] >= 0) atomicAdd(&h[dp[c] >> A_BSH], 1);
    __syncthreads();
    for (int b = t; b < A_KB; b += 1024) {
        int c = h[b];
        h[b] = c ? atomicAdd(&bcur[b], c) : 0;   // bucket-local base
    }
    __syncthreads();
    #pragma unroll
    for (int c = 0; c < 4; ++c) {
        if (dp[c] >= 0) {
            int b = dp[c] >> A_BSH;
            int loc = atomicAdd(&h[b], 1);       // LDS int atomic
            if (loc < A_CAP) {
                stg[b * A_CAP + loc] =
                    make_int2(sp[c] | ((dp[c] & (A_NPB - 1)) << 17),
                              __float_as_int(wp[c]));
            } else {
                int oi = atomicAdd(ovcnt, 1);
                if (oi < A_OVCAP) ovf[oi] = ebase + c;
            }
        }
    }
}

// fused per-bucket counting sort (LDS-resident) + quarter-wave gather, unroll 4
__global__ __launch_bounds__(1024) void k_sortgather(
    const ushort* __restrict__ xb, const int* __restrict__ bcur,
    const int2* __restrict__ stg, float* __restrict__ out) {
    __shared__ int2 buf[A_CAP];      // 16 KB raw payload
    __shared__ int2 srt[A_CAP];      // 16 KB sorted payload
    __shared__ int  hist[A_NPB];     // per-node counts
    __shared__ int  start[A_NPB];    // per-node exclusive offsets
    __shared__ int  cur[A_NPB];      // scan temp / place cursor
    int b = blockIdx.x, t = threadIdx.x;
    int cnt = bcur[b];
    if (cnt > A_CAP) cnt = A_CAP;
    int base = b * A_CAP;

    if (t < A_NPB) hist[t] = 0;
    __syncthreads();
    for (int i = t; i < cnt; i += 1024) {
        int2 p = stg[base + i];
        buf[i] = p;
        atomicAdd(&hist[(p.x >> 17) & (A_NPB - 1)], 1);
    }
    __syncthreads();
    // Hillis-Steele inclusive scan of 128 counts (threads 0..127)
    if (t < A_NPB) cur[t] = hist[t];
    __syncthreads();
    for (int off = 1; off < A_NPB; off <<= 1) {
        int v = (t < A_NPB && t >= off) ? cur[t - off] : 0;
        __syncthreads();
        if (t < A_NPB && t >= off) cur[t] += v;
        __syncthreads();
    }
    if (t < A_NPB) start[t] = (t == 0) ? 0 : cur[t - 1];
    __syncthreads();
    if (t < A_NPB) cur[t] = start[t];
    __syncthreads();
    // place into sorted LDS buffer
    for (int i = t; i < cnt; i += 1024) {
        int2 p = buf[i];
        int pos = atomicAdd(&cur[(p.x >> 17) & (A_NPB - 1)], 1);
        srt[pos] = p;
    }
    __syncthreads();

    // gather: 16 waves x 4 quarter-slots = 64 nodes per pass, 2 passes
    int wid  = t >> 6;                 // 0..15
    int lane = t & 63;
    int q    = lane >> 4;              // quarter slot
    int l    = lane & 15;              // ushort4 column
    const ushort4* xb4 = (const ushort4*)xb;
    #pragma unroll
    for (int pass = 0; pass < 2; ++pass) {
        int n = pass * 64 + wid * 4 + q;           // local node 0..127
        int node = (b << A_BSH) + n;
        int j = start[n], end = start[n] + hist[n];
        float a0[4] = {0.f, 0.f, 0.f, 0.f};
        float a1[4] = {0.f, 0.f, 0.f, 0.f};
        float a2[4] = {0.f, 0.f, 0.f, 0.f};
        float a3[4] = {0.f, 0.f, 0.f, 0.f};
        for (; j + 3 < end; j += 4) {
            int2 p0 = srt[j];
            int2 p1 = srt[j + 1];
            int2 p2 = srt[j + 2];
            int2 p3 = srt[j + 3];
            ushort4 u0 = xb4[(size_t)(p0.x & 0x1FFFF) * 16 + l];
            ushort4 u1 = xb4[(size_t)(p1.x & 0x1FFFF) * 16 + l];
            ushort4 u2 = xb4[(size_t)(p2.x & 0x1FFFF) * 16 + l];
            ushort4 u3 = xb4[(size_t)(p3.x & 0x1FFFF) * 16 + l];
            float w0 = __int_as_float(p0.y), w1 = __int_as_float(p1.y);
            float w2 = __int_as_float(p2.y), w3 = __int_as_float(p3.y);
            a0[0] += w0 * __uint_as_float((uint)u0.x << 16);
            a0[1] += w0 * __uint_as_float((uint)u0.y << 16);
            a0[2] += w0 * __uint_as_float((uint)u0.z << 16);
            a0[3] += w0 * __uint_as_float((uint)u0.w << 16);
            a1[0] += w1 * __uint_as_float((uint)u1.x << 16);
            a1[1] += w1 * __uint_as_float((uint)u1.y << 16);
            a1[2] += w1 * __uint_as_float((uint)u1.z << 16);
            a1[3] += w1 * __uint_as_float((uint)u1.w << 16);
            a2[0] += w2 * __uint_as_float((uint)u2.x << 16);
            a2[1] += w2 * __uint_as_float((uint)u2.y << 16);
            a2[2] += w2 * __uint_as_float((uint)u2.z << 16);
            a2[3] += w2 * __uint_as_float((uint)u2.w << 16);
            a3[0] += w3 * __uint_as_float((uint)u3.x << 16);
            a3[1] += w3 * __uint_as_float((uint)u3.y << 16);
            a3[2] += w3 * __uint_as_float((uint)u3.z << 16);
            a3[3] += w3 * __uint_as_float((uint)u3.w << 16);
        }
        for (; j < end; ++j) {
            int2 p = srt[j];
            ushort4 u = xb4[(size_t)(p.x & 0x1FFFF) * 16 + l];
            float wv = __int_as_float(p.y);
            a0[0] += wv * __uint_as_float((uint)u.x << 16);
            a0[1] += wv * __uint_as_float((uint)u.y << 16);
            a0[2] += wv * __uint_as_float((uint)u.z << 16);
            a0[3] += wv * __uint_as_float((uint)u.w << 16);
        }
        if (node < N_NODES) {
            float4 r;
            r.x = (a0[0] + a1[0]) + (a2[0] + a3[0]);
            r.y = (a0[1] + a1[1]) + (a2[1] + a3[1]);
            r.z = (a0[2] + a1[2]) + (a2[2] + a3[2]);
            r.w = (a0[3] + a1[3]) + (a2[3] + a3[3]);
            ((float4*)out)[(size_t)node * 16 + l] = r;
        }
    }
}

// overflow fix-up (normally 0 entries): exact fp32 atomic adds
__global__ __launch_bounds__(256) void k_ovf(
    const float* __restrict__ x, const int* __restrict__ ei,
    const float* __restrict__ w, const int* __restrict__ ovf,
    const int* __restrict__ ovcnt, float* __restrict__ out, int E) {
    int n = *ovcnt;
    if (n > A_OVCAP) n = A_OVCAP;
    int wid  = blockIdx.x * 4 + (threadIdx.x >> 6);
    int lane = threadIdx.x & 63;
    for (int i = wid; i < n; i += gridDim.x * 4) {
        int e = ovf[i];
        float v = w[e] * x[(size_t)ei[e] * N_FEAT + lane];
        atomicAdd(&out[(size_t)ei[E + e] * N_FEAT + lane], v);
    }
}

// ---------------- Path B (R4 exact pipeline, proven 200us) ----------------
#define BSH       8
#define NPB       (1 << BSH)
#define KB        ((N_NODES + NPB - 1) >> BSH)     // 391
#define FCHUNK    8192
#define SORT_CAP  4096

__global__ __launch_bounds__(256) void k_chist(
    const int* __restrict__ ei, int* __restrict__ bcur, int E) {
    __shared__ int h[KB];
    int t = threadIdx.x;
    for (int b = t; b < KB; b += 256) h[b] = 0;
    __syncthreads();
    int e0 = blockIdx.x * FCHUNK;
    #pragma unroll
    for (int k = 0; k < FCHUNK / 256; ++k) {
        int e = e0 + k * 256 + t;
        if (e < E) atomicAdd(&h[ei[E + e] >> BSH], 1);
    }
    __syncthreads();
    for (int b = t; b < KB; b += 256) if (h[b]) atomicAdd(&bcur[b], h[b]);
}

__global__ __launch_bounds__(256) void k_cscan(
    int* __restrict__ bcur, int* __restrict__ boffs) {
    __shared__ int sdata[256];
    int t = threadIdx.x;
    int i0 = 2 * t, i1 = 2 * t + 1;
    int v0 = (i0 < KB) ? bcur[i0] : 0;
    int v1 = (i1 < KB) ? bcur[i1] : 0;
    sdata[t] = v0 + v1; __syncthreads();
    for (int off = 1; off < 256; off <<= 1) {
        int v = (t >= off) ? sdata[t - off] : 0;
        __syncthreads();
        if (t >= off) sdata[t] += v;
        __syncthreads();
    }
    int run = (t == 0) ? 0 : sdata[t - 1];
    if (i0 < KB) { boffs[i0] = run; bcur[i0] = run; }
    run += v0;
    if (i1 < KB) { boffs[i1] = run; bcur[i1] = run; }
    if (t == 255) boffs[KB] = sdata[255];
}

__global__ __launch_bounds__(256) void k_cbin(
    const int* __restrict__ ei, const float* __restrict__ w,
    int* __restrict__ bcur, int2* __restrict__ stg, int E) {
    __shared__ int h[KB];
    int t = threadIdx.x;
    for (int b = t; b < KB; b += 256) h[b] = 0;
    __syncthreads();
    int e0 = blockIdx.x * FCHUNK;
    #pragma unroll
    for (int k = 0; k < FCHUNK / 256; ++k) {
        int e = e0 + k * 256 + t;
        if (e < E) atomicAdd(&h[ei[E + e] >> BSH], 1);
    }
    __syncthreads();
    for (int b = t; b < KB; b += 256) {
        int c = h[b];
        h[b] = c ? atomicAdd(&bcur[b], c) : 0;
    }
    __syncthreads();
    #pragma unroll
    for (int k = 0; k < FCHUNK / 256; ++k) {
        int e = e0 + k * 256 + t;
        if (e < E) {
            int dst = ei[E + e];
            int slot = atomicAdd(&h[dst >> BSH], 1);
            stg[slot] = make_int2(ei[e] | ((dst & (NPB - 1)) << 17),
                                  __float_as_int(w[e]));
        }
    }
}

__global__ __launch_bounds__(256) void k_csort(
    int2* __restrict__ stg, const int* __restrict__ boffs,
    int* __restrict__ offs) {
    __shared__ int2 buf[SORT_CAP];
    __shared__ int  hist[NPB];
    __shared__ int  cur[NPB];
    __shared__ int  sdata[256];
    int b = blockIdx.x, t = threadIdx.x;
    int bg = boffs[b], end = boffs[b + 1], cnt = end - bg;
    for (int n = t; n < NPB; n += 256) hist[n] = 0;
    __syncthreads();
    int nlds = cnt < SORT_CAP ? cnt : SORT_CAP;
    for (int i = t; i < nlds; i += 256) {
        int2 p = stg[bg + i];
        buf[i] = p;
        atomicAdd(&hist[(p.x >> 17) & (NPB - 1)], 1);
    }
    int2 r0{0,0}, r1{0,0}; int nr = 0;
    {
        int i0 = nlds + t, i1 = nlds + 256 + t;
        if (i0 < cnt) { r0 = stg[bg + i0]; atomicAdd(&hist[(r0.x >> 17) & (NPB - 1)], 1); nr = 1; }
        if (i1 < cnt) { r1 = stg[bg + i1]; atomicAdd(&hist[(r1.x >> 17) & (NPB - 1)], 1); nr = 2; }
    }
    __syncthreads();
    int c = hist[t];
    sdata[t] = c; __syncthreads();
    for (int off = 1; off < 256; off <<= 1) {
        int v = (t >= off) ? sdata[t - off] : 0;
        __syncthreads();
        if (t >= off) sdata[t] += v;
        __syncthreads();
    }
    int excl = (t == 0) ? 0 : sdata[t - 1];
    cur[t] = excl;
    int node = (b << BSH) + t;
    if (node < N_NODES) offs[node] = bg + excl;
    if (b == KB - 1 && t == 255) offs[N_NODES] = end;
    __syncthreads();
    for (int i = t; i < nlds; i += 256) {
        int2 p = buf[i];
        int pos = atomicAdd(&cur[(p.x >> 17) & (NPB - 1)], 1);
        stg[bg + pos] = p;
    }
    if (nr >= 1) { int pos = atomicAdd(&cur[(r0.x >> 17) & (NPB - 1)], 1); stg[bg + pos] = r0; }
    if (nr >= 2) { int pos = atomicAdd(&cur[(r1.x >> 17) & (NPB - 1)], 1); stg[bg + pos] = r1; }
}

__global__ __launch_bounds__(256) void k_gather(
    const float* __restrict__ x, const int* __restrict__ offs,
    const int2* __restrict__ stg, float* __restrict__ out) {
    int node = blockIdx.x * 4 + (threadIdx.x >> 6);
    int lane = threadIdx.x & 63;
    if (node >= N_NODES) return;
    int bg = offs[node], end = offs[node + 1];
    float a0 = 0.f, a1 = 0.f, a2 = 0.f, a3 = 0.f;
    int j = bg;
    for (; j + 3 < end; j += 4) {
        int2 p0 = stg[j];
        int2 p1 = stg[j + 1];
        int2 p2 = stg[j + 2];
        int2 p3 = stg[j + 3];
        a0 += __int_as_float(p0.y) * x[(size_t)(p0.x & 0x1FFFF) * N_FEAT + lane];
        a1 += __int_as_float(p1.y) * x[(size_t)(p1.x & 0x1FFFF) * N_FEAT + lane];
        a2 += __int_as_float(p2.y) * x[(size_t)(p2.x & 0x1FFFF) * N_FEAT + lane];
        a3 += __int_as_float(p3.y) * x[(size_t)(p3.x & 0x1FFFF) * N_FEAT + lane];
    }
    for (; j < end; ++j) {
        int2 p = stg[j];
        a0 += __int_as_float(p.y) * x[(size_t)(p.x & 0x1FFFF) * N_FEAT + lane];
    }
    out[(size_t)node * N_FEAT + lane] = (a0 + a1) + (a2 + a3);
}

// ---------------- Path C (R1 scatter) ----------------
__global__ __launch_bounds__(256) void gnn_scatter_kernel(
    const float* __restrict__ x, const int* __restrict__ ei,
    const float* __restrict__ w, float* __restrict__ out, int E) {
    int e = blockIdx.x * 4 + (threadIdx.x >> 6);
    int lane = threadIdx.x & 63;
    if (e >= E) return;
    float v = w[e] * x[(size_t)ei[e] * N_FEAT + lane];
    atomicAdd(&out[(size_t)ei[E + e] * N_FEAT + lane], v);
}

static inline size_t align16(size_t v) { return (v + 15) & ~(size_t)15; }

extern "C" void kernel_launch(void* const* d_in, const int* in_sizes, int n_in,
                              void* d_out, int out_size, void* d_ws, size_t ws_size,
                              hipStream_t stream) {
    const float* x   = (const float*)d_in[0];
    const int*   ei  = (const int*)d_in[1];
    const float* w   = (const float*)d_in[2];
    float*       out = (float*)d_out;
    const int E = in_sizes[2];
    char* ws = (char*)d_ws;

    // ---- Path A layout ----
    size_t a_xb   = 0;
    size_t a_stg  = align16(a_xb + (size_t)N_NODES * N_FEAT * 2);
    size_t a_bcur = align16(a_stg + (size_t)A_KB * A_CAP * 8);    // KB ints + ovcnt
    size_t a_ovf  = align16(a_bcur + (size_t)(A_KB + 1) * 4);
    size_t need_a = a_ovf + (size_t)A_OVCAP * 4;

    if (ws_size >= need_a && E == 1250000) {
        ushort* xb    = (ushort*)(ws + a_xb);
        int2*   stg   = (int2*)(ws + a_stg);
        int*    bcur  = (int*)(ws + a_bcur);
        int*    ovcnt = bcur + A_KB;
        int*    ovf   = (int*)(ws + a_ovf);

        hipMemsetAsync(bcur, 0, (size_t)(A_KB + 1) * 4, stream);
        k_castbin<<<NBIN + NCAST, 1024, 0, stream>>>(
            x, xb, ei, w, bcur, stg, ovf, ovcnt, E);
        k_sortgather<<<A_KB, 1024, 0, stream>>>(xb, bcur, stg, out);
        k_ovf<<<16, 256, 0, stream>>>(x, ei, w, ovf, ovcnt, out, E);
        return;
    }

    // ---- Path B layout (R4) ----
    size_t b_bcur  = 0;
    size_t b_boffs = align16(b_bcur + (size_t)KB * 4);
    size_t b_offs  = align16(b_boffs + (size_t)(KB + 1) * 4);
    size_t b_stg   = align16(b_offs + (size_t)(N_NODES + 1) * 4);
    size_t need_b  = b_stg + (size_t)E * 8;

    if (ws_size >= need_b) {
        int*  bcur  = (int*)(ws + b_bcur);
        int*  boffs = (int*)(ws + b_boffs);
        int*  offs  = (int*)(ws + b_offs);
        int2* stg   = (int2*)(ws + b_stg);
        const int nblk = (E + FCHUNK - 1) / FCHUNK;
        hipMemsetAsync(bcur, 0, (size_t)KB * 4, stream);
        k_chist<<<nblk, 256, 0, stream>>>(ei, bcur, E);
        k_cscan<<<1, 256, 0, stream>>>(bcur, boffs);
        k_cbin<<<nblk, 256, 0, stream>>>(ei, w, bcur, stg, E);
        k_csort<<<KB, 256, 0, stream>>>(stg, boffs, offs);
        k_gather<<<(N_NODES + 3) / 4, 256, 0, stream>>>(x, offs, stg, out);
        return;
    }

    // ---- Path C ----
    hipMemsetAsync(d_out, 0, (size_t)out_size * sizeof(float), stream);
    gnn_scatter_kernel<<<(E + 3) / 4, 256, 0, stream>>>(x, ei, w, out, E);
}

// Round 10
// 135.830 us; speedup vs baseline: 1.0679x; 1.0356x over previous
//
#include <hip/hip_runtime.h>
#include <hip/hip_bf16.h>

// LightGCNConv: out[dst] = sum_e w[e] * x[src_e], N=100000, d=64, E=1250000.
//
// R1: 80M fp32 device atomics -> 275us kernel (atomics bypass cache; WRITE=320MB).
// R2: exact CSR; fill 8x write amp 90us + gather 88us -> 295 total.
// R3: per-bucket LDS-accumulate gather, 1563 blocks -> 471us. REVERTED.
// R4: L2-resident CSR build + reg-accumulate gather -> 200 total.
// R5: bf16 x + fixed-cap buckets -> 158.7. Harness poison/restore of 256MiB
//     d_ws + inputs = ~65-70us fixed overhead inside dur_us.
// R6: cast+bin fusion, 4-node/wave gather -> 158.4 (neutral).
// R7: sort+gather fused per bucket (sorted payload LDS-resident) -> 135.6 BEST.
// R8: octant gather + bitonic degree-sort -> 145.1 REGRESSION (VGPR + barriers;
//     scattered-gather cost is per distinct 128B segment, not per instruction).
// R9: unroll-4 + int4 castbin -> 140.7 REGRESSION (~half fill-drift noise;
//     unroll-4 VGPR pressure for latency already covered by 16-wave occupancy).
// R10: EXACT R7 revert (best-known). Structural floor analysis:
//     ~65-70us harness poison/restore + ~25us bin + ~40us gather (160MB of
//     random 128B rows from 12.8MB working set: >4MiB/XCD L2 -> ~30% hit,
//     L3-latency-bound ~4TB/s effective). R6-R9 shows lane-layout/unroll/
//     issue tweaks move this <=+-4%. If this reproduces ~135us -> ceiling.
//     Fallback chain: A -> B (R4 exact, proven) -> C (R1).

#define N_NODES   100000
#define N_FEAT    64

// ---------------- Path A ----------------
#define A_BSH     7
#define A_NPB     (1 << A_BSH)                       // 128 nodes/bucket
#define A_KB      ((N_NODES + A_NPB - 1) >> A_BSH)   // 782 buckets
#define A_CAP     2048                               // slots/bucket (mean 1598)
#define A_FCHUNK  4096                               // edges per bin block
#define A_OVCAP   65536
#define NBIN      ((1250000 + A_FCHUNK - 1) / A_FCHUNK)   // 306 (E known)
#define NCAST     391   // 391*1024*4 float4 = 1.6016M >= 1.6M

// fused: blocks [0,NBIN) bin edges; blocks [NBIN,NBIN+NCAST) cast x->bf16
__global__ __launch_bounds__(1024) void k_castbin(
    const float* __restrict__ x, ushort* __restrict__ xb,
    const int* __restrict__ ei, const float* __restrict__ w,
    int* __restrict__ bcur, int2* __restrict__ stg,
    int* __restrict__ ovf, int* __restrict__ ovcnt, int E) {
    int t = threadIdx.x;
    if (blockIdx.x >= NBIN) {
        // ---- cast role ----
        int cb = blockIdx.x - NBIN;
        #pragma unroll
        for (int k = 0; k < 4; ++k) {
            int i4 = cb * 4096 + k * 1024 + t;           // float4 index
            if (i4 < N_NODES * N_FEAT / 4) {
                float4 v = ((const float4*)x)[i4];
                uint4 u = *(uint4*)&v;
                ushort4 r;
                r.x = (ushort)((u.x + 0x7FFFu + ((u.x >> 16) & 1)) >> 16);
                r.y = (ushort)((u.y + 0x7FFFu + ((u.y >> 16) & 1)) >> 16);
                r.z = (ushort)((u.z + 0x7FFFu + ((u.z >> 16) & 1)) >> 16);
                r.w = (ushort)((u.w + 0x7FFFu + ((u.w >> 16) & 1)) >> 16);
                ((ushort4*)xb)[i4] = r;
            }
        }
        return;
    }
    // ---- bin role: single register-staged read of dst/src/w ----
    __shared__ int h[A_KB];
    for (int b = t; b < A_KB; b += 1024) h[b] = 0;
    __syncthreads();
    int e0 = blockIdx.x * A_FCHUNK;
    int dstv[A_FCHUNK / 1024];
    int srcv[A_FCHUNK / 1024];
    float wv[A_FCHUNK / 1024];
    #pragma unroll
    for (int k = 0; k < A_FCHUNK / 1024; ++k) {
        int e = e0 + k * 1024 + t;
        bool ok = (e < E);
        dstv[k] = ok ? ei[E + e] : -1;
        srcv[k] = ok ? ei[e] : 0;
        wv[k]   = ok ? w[e] : 0.f;
        if (ok) atomicAdd(&h[dstv[k] >> A_BSH], 1);
    }
    __syncthreads();
    for (int b = t; b < A_KB; b += 1024) {
        int c = h[b];
        h[b] = c ? atomicAdd(&bcur[b], c) : 0;   // bucket-local base
    }
    __syncthreads();
    #pragma unroll
    for (int k = 0; k < A_FCHUNK / 1024; ++k) {
        if (dstv[k] >= 0) {
            int b = dstv[k] >> A_BSH;
            int loc = atomicAdd(&h[b], 1);       // LDS int atomic
            if (loc < A_CAP) {
                stg[b * A_CAP + loc] =
                    make_int2(srcv[k] | ((dstv[k] & (A_NPB - 1)) << 17),
                              __float_as_int(wv[k]));
            } else {
                int oi = atomicAdd(ovcnt, 1);
                if (oi < A_OVCAP) ovf[oi] = e0 + k * 1024 + t;
            }
        }
    }
}

// fused per-bucket counting sort (LDS-resident) + quarter-wave gather
__global__ __launch_bounds__(1024) void k_sortgather(
    const ushort* __restrict__ xb, const int* __restrict__ bcur,
    const int2* __restrict__ stg, float* __restrict__ out) {
    __shared__ int2 buf[A_CAP];      // 16 KB raw payload
    __shared__ int2 srt[A_CAP];      // 16 KB sorted payload
    __shared__ int  hist[A_NPB];     // per-node counts
    __shared__ int  start[A_NPB];    // per-node exclusive offsets
    __shared__ int  cur[A_NPB];      // scan temp / place cursor
    int b = blockIdx.x, t = threadIdx.x;
    int cnt = bcur[b];
    if (cnt > A_CAP) cnt = A_CAP;
    int base = b * A_CAP;

    if (t < A_NPB) hist[t] = 0;
    __syncthreads();
    for (int i = t; i < cnt; i += 1024) {
        int2 p = stg[base + i];
        buf[i] = p;
        atomicAdd(&hist[(p.x >> 17) & (A_NPB - 1)], 1);
    }
    __syncthreads();
    // Hillis-Steele inclusive scan of 128 counts (threads 0..127)
    if (t < A_NPB) cur[t] = hist[t];
    __syncthreads();
    for (int off = 1; off < A_NPB; off <<= 1) {
        int v = (t < A_NPB && t >= off) ? cur[t - off] : 0;
        __syncthreads();
        if (t < A_NPB && t >= off) cur[t] += v;
        __syncthreads();
    }
    if (t < A_NPB) start[t] = (t == 0) ? 0 : cur[t - 1];
    __syncthreads();
    if (t < A_NPB) cur[t] = start[t];
    __syncthreads();
    // place into sorted LDS buffer
    for (int i = t; i < cnt; i += 1024) {
        int2 p = buf[i];
        int pos = atomicAdd(&cur[(p.x >> 17) & (A_NPB - 1)], 1);
        srt[pos] = p;
    }
    __syncthreads();

    // gather: 16 waves x 4 quarter-slots = 64 nodes per pass, 2 passes
    int wid  = t >> 6;                 // 0..15
    int lane = t & 63;
    int q    = lane >> 4;              // quarter slot
    int l    = lane & 15;              // ushort4 column
    const ushort4* xb4 = (const ushort4*)xb;
    #pragma unroll
    for (int pass = 0; pass < 2; ++pass) {
        int n = pass * 64 + wid * 4 + q;           // local node 0..127
        int node = (b << A_BSH) + n;
        int j = start[n], end = start[n] + hist[n];
        float ax0 = 0.f, ay0 = 0.f, az0 = 0.f, aw0 = 0.f;
        float ax1 = 0.f, ay1 = 0.f, az1 = 0.f, aw1 = 0.f;
        for (; j + 1 < end; j += 2) {
            int2 p0 = srt[j];
            int2 p1 = srt[j + 1];
            ushort4 u0 = xb4[(size_t)(p0.x & 0x1FFFF) * 16 + l];
            ushort4 u1 = xb4[(size_t)(p1.x & 0x1FFFF) * 16 + l];
            float w0 = __int_as_float(p0.y), w1 = __int_as_float(p1.y);
            ax0 += w0 * __uint_as_float((uint)u0.x << 16);
            ay0 += w0 * __uint_as_float((uint)u0.y << 16);
            az0 += w0 * __uint_as_float((uint)u0.z << 16);
            aw0 += w0 * __uint_as_float((uint)u0.w << 16);
            ax1 += w1 * __uint_as_float((uint)u1.x << 16);
            ay1 += w1 * __uint_as_float((uint)u1.y << 16);
            az1 += w1 * __uint_as_float((uint)u1.z << 16);
            aw1 += w1 * __uint_as_float((uint)u1.w << 16);
        }
        if (j < end) {
            int2 p = srt[j];
            ushort4 u = xb4[(size_t)(p.x & 0x1FFFF) * 16 + l];
            float wvv = __int_as_float(p.y);
            ax0 += wvv * __uint_as_float((uint)u.x << 16);
            ay0 += wvv * __uint_as_float((uint)u.y << 16);
            az0 += wvv * __uint_as_float((uint)u.z << 16);
            aw0 += wvv * __uint_as_float((uint)u.w << 16);
        }
        if (node < N_NODES) {
            float4 r;
            r.x = ax0 + ax1; r.y = ay0 + ay1;
            r.z = az0 + az1; r.w = aw0 + aw1;
            ((float4*)out)[(size_t)node * 16 + l] = r;
        }
    }
}

// overflow fix-up (normally 0 entries): exact fp32 atomic adds
__global__ __launch_bounds__(256) void k_ovf(
    const float* __restrict__ x, const int* __restrict__ ei,
    const float* __restrict__ w, const int* __restrict__ ovf,
    const int* __restrict__ ovcnt, float* __restrict__ out, int E) {
    int n = *ovcnt;
    if (n > A_OVCAP) n = A_OVCAP;
    int wid  = blockIdx.x * 4 + (threadIdx.x >> 6);
    int lane = threadIdx.x & 63;
    for (int i = wid; i < n; i += gridDim.x * 4) {
        int e = ovf[i];
        float v = w[e] * x[(size_t)ei[e] * N_FEAT + lane];
        atomicAdd(&out[(size_t)ei[E + e] * N_FEAT + lane], v);
    }
}

// ---------------- Path B (R4 exact pipeline, proven 200us) ----------------
#define BSH       8
#define NPB       (1 << BSH)
#define KB        ((N_NODES + NPB - 1) >> BSH)     // 391
#define FCHUNK    8192
#define SORT_CAP  4096

__global__ __launch_bounds__(256) void k_chist(
    const int* __restrict__ ei, int* __restrict__ bcur, int E) {
    __shared__ int h[KB];
    int t = threadIdx.x;
    for (int b = t; b < KB; b += 256) h[b] = 0;
    __syncthreads();
    int e0 = blockIdx.x * FCHUNK;
    #pragma unroll
    for (int k = 0; k < FCHUNK / 256; ++k) {
        int e = e0 + k * 256 + t;
        if (e < E) atomicAdd(&h[ei[E + e] >> BSH], 1);
    }
    __syncthreads();
    for (int b = t; b < KB; b += 256) if (h[b]) atomicAdd(&bcur[b], h[b]);
}

__global__ __launch_bounds__(256) void k_cscan(
    int* __restrict__ bcur, int* __restrict__ boffs) {
    __shared__ int sdata[256];
    int t = threadIdx.x;
    int i0 = 2 * t, i1 = 2 * t + 1;
    int v0 = (i0 < KB) ? bcur[i0] : 0;
    int v1 = (i1 < KB) ? bcur[i1] : 0;
    sdata[t] = v0 + v1; __syncthreads();
    for (int off = 1; off < 256; off <<= 1) {
        int v = (t >= off) ? sdata[t - off] : 0;
        __syncthreads();
        if (t >= off) sdata[t] += v;
        __syncthreads();
    }
    int run = (t == 0) ? 0 : sdata[t - 1];
    if (i0 < KB) { boffs[i0] = run; bcur[i0] = run; }
    run += v0;
    if (i1 < KB) { boffs[i1] = run; bcur[i1] = run; }
    if (t == 255) boffs[KB] = sdata[255];
}

__global__ __launch_bounds__(256) void k_cbin(
    const int* __restrict__ ei, const float* __restrict__ w,
    int* __restrict__ bcur, int2* __restrict__ stg, int E) {
    __shared__ int h[KB];
    int t = threadIdx.x;
    for (int b = t; b < KB; b += 256) h[b] = 0;
    __syncthreads();
    int e0 = blockIdx.x * FCHUNK;
    #pragma unroll
    for (int k = 0; k < FCHUNK / 256; ++k) {
        int e = e0 + k * 256 + t;
        if (e < E) atomicAdd(&h[ei[E + e] >> BSH], 1);
    }
    __syncthreads();
    for (int b = t; b < KB; b += 256) {
        int c = h[b];
        h[b] = c ? atomicAdd(&bcur[b], c) : 0;
    }
    __syncthreads();
    #pragma unroll
    for (int k = 0; k < FCHUNK / 256; ++k) {
        int e = e0 + k * 256 + t;
        if (e < E) {
            int dst = ei[E + e];
            int slot = atomicAdd(&h[dst >> BSH], 1);
            stg[slot] = make_int2(ei[e] | ((dst & (NPB - 1)) << 17),
                                  __float_as_int(w[e]));
        }
    }
}

__global__ __launch_bounds__(256) void k_csort(
    int2* __restrict__ stg, const int* __restrict__ boffs,
    int* __restrict__ offs) {
    __shared__ int2 buf[SORT_CAP];
    __shared__ int  hist[NPB];
    __shared__ int  cur[NPB];
    __shared__ int  sdata[256];
    int b = blockIdx.x, t = threadIdx.x;
    int bg = boffs[b], end = boffs[b + 1], cnt = end - bg;
    for (int n = t; n < NPB; n += 256) hist[n] = 0;
    __syncthreads();
    int nlds = cnt < SORT_CAP ? cnt : SORT_CAP;
    for (int i = t; i < nlds; i += 256) {
        int2 p = stg[bg + i];
        buf[i] = p;
        atomicAdd(&hist[(p.x >> 17) & (NPB - 1)], 1);
    }
    int2 r0{0,0}, r1{0,0}; int nr = 0;
    {
        int i0 = nlds + t, i1 = nlds + 256 + t;
        if (i0 < cnt) { r0 = stg[bg + i0]; atomicAdd(&hist[(r0.x >> 17) & (NPB - 1)], 1); nr = 1; }
        if (i1 < cnt) { r1 = stg[bg + i1]; atomicAdd(&hist[(r1.x >> 17) & (NPB - 1)], 1); nr = 2; }
    }
    __syncthreads();
    int c = hist[t];
    sdata[t] = c; __syncthreads();
    for (int off = 1; off < 256; off <<= 1) {
        int v = (t >= off) ? sdata[t - off] : 0;
        __syncthreads();
        if (t >= off) sdata[t] += v;
        __syncthreads();
    }
    int excl = (t == 0) ? 0 : sdata[t - 1];
    cur[t] = excl;
    int node = (b << BSH) + t;
    if (node < N_NODES) offs[node] = bg + excl;
    if (b == KB - 1 && t == 255) offs[N_NODES] = end;
    __syncthreads();
    for (int i = t; i < nlds; i += 256) {
        int2 p = buf[i];
        int pos = atomicAdd(&cur[(p.x >> 17) & (NPB - 1)], 1);
        stg[bg + pos] = p;
    }
    if (nr >= 1) { int pos = atomicAdd(&cur[(r0.x >> 17) & (NPB - 1)], 1); stg[bg + pos] = r0; }
    if (nr >= 2) { int pos = atomicAdd(&cur[(r1.x >> 17) & (NPB - 1)], 1); stg[bg + pos] = r1; }
}

__global__ __launch_bounds__(256) void k_gather(
    const float* __restrict__ x, const int* __restrict__ offs,
    const int2* __restrict__ stg, float* __restrict__ out) {
    int node = blockIdx.x * 4 + (threadIdx.x >> 6);
    int lane = threadIdx.x & 63;
    if (node >= N_NODES) return;
    int bg = offs[node], end = offs[node + 1];
    float a0 = 0.f, a1 = 0.f, a2 = 0.f, a3 = 0.f;
    int j = bg;
    for (; j + 3 < end; j += 4) {
        int2 p0 = stg[j];
        int2 p1 = stg[j + 1];
        int2 p2 = stg[j + 2];
        int2 p3 = stg[j + 3];
        a0 += __int_as_float(p0.y) * x[(size_t)(p0.x & 0x1FFFF) * N_FEAT + lane];
        a1 += __int_as_float(p1.y) * x[(size_t)(p1.x & 0x1FFFF) * N_FEAT + lane];
        a2 += __int_as_float(p2.y) * x[(size_t)(p2.x & 0x1FFFF) * N_FEAT + lane];
        a3 += __int_as_float(p3.y) * x[(size_t)(p3.x & 0x1FFFF) * N_FEAT + lane];
    }
    for (; j < end; ++j) {
        int2 p = stg[j];
        a0 += __int_as_float(p.y) * x[(size_t)(p.x & 0x1FFFF) * N_FEAT + lane];
    }
    out[(size_t)node * N_FEAT + lane] = (a0 + a1) + (a2 + a3);
}

// ---------------- Path C (R1 scatter) ----------------
__global__ __launch_bounds__(256) void gnn_scatter_kernel(
    const float* __restrict__ x, const int* __restrict__ ei,
    const float* __restrict__ w, float* __restrict__ out, int E) {
    int e = blockIdx.x * 4 + (threadIdx.x >> 6);
    int lane = threadIdx.x & 63;
    if (e >= E) return;
    float v = w[e] * x[(size_t)ei[e] * N_FEAT + lane];
    atomicAdd(&out[(size_t)ei[E + e] * N_FEAT + lane], v);
}

static inline size_t align16(size_t v) { return (v + 15) & ~(size_t)15; }

extern "C" void kernel_launch(void* const* d_in, const int* in_sizes, int n_in,
                              void* d_out, int out_size, void* d_ws, size_t ws_size,
                              hipStream_t stream) {
    const float* x   = (const float*)d_in[0];
    const int*   ei  = (const int*)d_in[1];
    const float* w   = (const float*)d_in[2];
    float*       out = (float*)d_out;
    const int E = in_sizes[2];
    char* ws = (char*)d_ws;

    // ---- Path A layout ----
    size_t a_xb   = 0;
    size_t a_stg  = align16(a_xb + (size_t)N_NODES * N_FEAT * 2);
    size_t a_bcur = align16(a_stg + (size_t)A_KB * A_CAP * 8);    // KB ints + ovcnt
    size_t a_ovf  = align16(a_bcur + (size_t)(A_KB + 1) * 4);
    size_t need_a = a_ovf + (size_t)A_OVCAP * 4;

    if (ws_size >= need_a && E == 1250000) {
        ushort* xb    = (ushort*)(ws + a_xb);
        int2*   stg   = (int2*)(ws + a_stg);
        int*    bcur  = (int*)(ws + a_bcur);
        int*    ovcnt = bcur + A_KB;
        int*    ovf   = (int*)(ws + a_ovf);

        hipMemsetAsync(bcur, 0, (size_t)(A_KB + 1) * 4, stream);
        k_castbin<<<NBIN + NCAST, 1024, 0, stream>>>(
            x, xb, ei, w, bcur, stg, ovf, ovcnt, E);
        k_sortgather<<<A_KB, 1024, 0, stream>>>(xb, bcur, stg, out);
        k_ovf<<<16, 256, 0, stream>>>(x, ei, w, ovf, ovcnt, out, E);
        return;
    }

    // ---- Path B layout (R4) ----
    size_t b_bcur  = 0;
    size_t b_boffs = align16(b_bcur + (size_t)KB * 4);
    size_t b_offs  = align16(b_boffs + (size_t)(KB + 1) * 4);
    size_t b_stg   = align16(b_offs + (size_t)(N_NODES + 1) * 4);
    size_t need_b  = b_stg + (size_t)E * 8;

    if (ws_size >= need_b) {
        int*  bcur  = (int*)(ws + b_bcur);
        int*  boffs = (int*)(ws + b_boffs);
        int*  offs  = (int*)(ws + b_offs);
        int2* stg   = (int2*)(ws + b_stg);
        const int nblk = (E + FCHUNK - 1) / FCHUNK;
        hipMemsetAsync(bcur, 0, (size_t)KB * 4, stream);
        k_chist<<<nblk, 256, 0, stream>>>(ei, bcur, E);
        k_cscan<<<1, 256, 0, stream>>>(bcur, boffs);
        k_cbin<<<nblk, 256, 0, stream>>>(ei, w, bcur, stg, E);
        k_csort<<<KB, 256, 0, stream>>>(stg, boffs, offs);
        k_gather<<<(N_NODES + 3) / 4, 256, 0, stream>>>(x, offs, stg, out);
        return;
    }

    // ---- Path C ----
    hipMemsetAsync(d_out, 0, (size_t)out_size * sizeof(float), stream);
    gnn_scatter_kernel<<<(E + 3) / 4, 256, 0, stream>>>(x, ei, w, out, E);
}